// Round 11
// baseline (74.621 us; speedup 1.0000x reference)
//
#include <hip/hip_runtime.h>

// MTCNN proposal stage: score threshold + greedy NMS + bbox regression, 96x96.
//
// Validated-exact facts (R1-R10 passed, absmax 0.0):
//  - All boxes 21x21 (area 441), pitch 3/4/3 (period 3). IoU>0.5 <=> inter>294.
//  - Suppression pairs only at 12 offsets {+-1,+-2 axial, +-1 diagonal} with an
//    index%3 geometry rule => pure bit logic, no float IoU.
//  - Greedy NMS == unique fixpoint of monotone 3-state relaxation over the
//    dominance graph (priority = score desc, index asc; ties on negative
//    offsets use >=). Bitboard Jacobi with in-place updates is race-benign;
//    any interleaving of final decisions is sound (multi-eval validated).
//
// Structure (R10): 9 blocks each redundantly compute the full NMS fixpoint in
// their own LDS (deterministic => identical), then each block epilogues its
// own 1024-cell slice. One dispatch, zero inter-block communication.
// R11: (1) round-0 seeding — K initialized with ballot(valid && mask==0)
// (empty-dominator cells are kept by definition), removing 1-2 all-active
// early rounds; (2) QUAD-eval per barrier (4 graph-steps/barrier => ~10
// barriers); (3) epilogue prep hoisted before the rounds loop (non-eval
// waves compute it in barrier slack).
// Kept: LDS-only barriers (no vmcnt drain), guard-row clamp-free mask build,
// register-lean sliding-window eval, pair-indexed period-3 term flags.

namespace {

constexpr int Hh = 96, Ww = 96, Nn = Hh * Ww;   // 9216
constexpr int NW = Nn / 64;                      // 144 words
constexpr int GUARD = 2 * Ww;                    // 192 floats each side
constexpr float THR_SCORE = 0.6f;
constexpr int NT = 1024;
constexpr int NBLK = Nn / NT;                    // 9 blocks, 1 cell/thread each

typedef float v4a __attribute__((ext_vector_type(4), aligned(4)));

// LDS-only barrier: s_waitcnt lgkmcnt(0) + s_barrier; leaves vmcnt untouched.
__device__ __forceinline__ void lds_barrier() {
  __builtin_amdgcn_fence(__ATOMIC_RELEASE, "workgroup", "local");
  __builtin_amdgcn_s_barrier();
  __builtin_amdgcn_fence(__ATOMIC_ACQUIRE, "workgroup", "local");
}

__global__ __launch_bounds__(NT, 4) void mtcnn_kernel(
    const float* __restrict__ cls,
    const float* __restrict__ bbox,
    float* __restrict__ out)
{
  __shared__ __attribute__((aligned(16))) float s_scp[Nn + 2 * GUARD]; // guarded scores
  __shared__ unsigned long long s_D[12][NW];      // dominance bitmaps
  __shared__ unsigned long long s_Up[NW + 8];     // UNDEC, 4 guard words/side
  __shared__ unsigned long long s_Kp[NW + 8];     // KEPT
  __shared__ int s_ch[3];                         // period-3 PAIR change flags

  float* const sc = s_scp + GUARD;
  unsigned long long* const U = s_Up + 4;
  unsigned long long* const K = s_Kp + 4;

  const int tid = threadIdx.x;
  const int lane = tid & 63;
  const int OFF[12] = {-1, 1, -2, 2, -Ww, Ww, -2*Ww, 2*Ww, -Ww-1, -Ww+1, Ww-1, Ww+1};

  // ---- Phase 1: stage scores, fill guards, zero bitmap guards/flags ----
  for (int q = tid; q < Nn / 4; q += NT)
    reinterpret_cast<v4a*>(sc)[q] = reinterpret_cast<const v4a*>(cls)[q];
  if (tid < GUARD) {                 // -1.0f guards: never pass >0.6 check
    s_scp[tid] = -1.0f;
    s_scp[GUARD + Nn + tid] = -1.0f;
  }
  if (tid < 4) {
    s_Up[tid] = 0ull; s_Kp[tid] = 0ull;
    s_Up[4 + NW + tid] = 0ull; s_Kp[4 + NW + tid] = 0ull;
  }
  if (tid < 3) s_ch[tid] = 0;
  lds_barrier();

  // ---- Prefetch THIS BLOCK'S bbox cell; in flight through phase 2+rounds
  const int ncell = blockIdx.x * NT + tid;        // this thread's epilogue cell
  v4a bb0 = reinterpret_cast<const v4a*>(bbox)[ncell];
  __builtin_amdgcn_sched_barrier(0);   // pin issue point; don't sink the load

  // ---- Phase 2: dominance masks -> ballots, with round-0 seeding ----
  for (int n = tid; n < Nn; n += NT) {
    float si = sc[n];
    unsigned int m = 0;
    bool valid = si > THR_SCORE;
    if (valid) {
      int r = n / Ww, c = n - r * Ww;
      int rm = r % 3, cm = c % 3;
      unsigned int geom = (1u << 0) | (1u << 1) | (1u << 4) | (1u << 5);
      if (cm == 1) geom |= 1u << 2;
      if (cm == 2) geom |= 1u << 3;
      if (rm == 1) geom |= 1u << 6;
      if (rm == 2) geom |= 1u << 7;
      if (!(rm == 2 && cm == 2)) geom |= 1u << 8;
      if (!(rm == 2 && cm == 1)) geom |= 1u << 9;
      if (!(rm == 1 && cm == 2)) geom |= 1u << 10;
      if (!(rm == 1 && cm == 1)) geom |= 1u << 11;
      unsigned int inb = 0;
      bool cge1 = c >= 1, cle = c <= Ww - 2, rge1 = r >= 1, rle = r <= Hh - 2;
      if (cge1) inb |= 1u << 0;
      if (cle)  inb |= 1u << 1;
      if (c >= 2)      inb |= 1u << 2;
      if (c <= Ww - 3) inb |= 1u << 3;
      if (rge1) inb |= 1u << 4;
      if (rle)  inb |= 1u << 5;
      if (r >= 2)      inb |= 1u << 6;
      if (r <= Hh - 3) inb |= 1u << 7;
      if (rge1 && cge1) inb |= 1u << 8;
      if (rge1 && cle)  inb |= 1u << 9;
      if (rle && cge1)  inb |= 1u << 10;
      if (rle && cle)   inb |= 1u << 11;
      unsigned int cand = geom & inb;
      #pragma unroll
      for (int b = 0; b < 12; ++b) {
        float sj = sc[n + OFF[b]];           // guards make this always in-array
        bool ge = (b == 0) | (b == 2) | (b == 4) | (b == 6) | (b == 8) | (b == 9);
        bool dom = ge ? (sj >= si) : (sj > si);
        if (((cand >> b) & 1u) && (sj > THR_SCORE) && dom) m |= 1u << b;
      }
    }
    int w = n >> 6;
    #pragma unroll
    for (int b = 0; b < 12; ++b) {
      unsigned long long bb2 = __ballot((m >> b) & 1u);
      if (lane == 0) s_D[b][w] = bb2;
    }
    // Round-0 seed: empty-dominator valid cells are KEPT by definition.
    unsigned long long ub = __ballot(valid && m != 0);
    unsigned long long kb = __ballot(valid && m == 0);
    if (lane == 0) { U[w] = ub; K[w] = kb; }
  }

  // ---- Epilogue prep (independent of K): hoisted before rounds so the 13
  //      non-eval waves compute it in barrier slack. ----
  float ex1, ex2, ey1, ey2, ebw, ebh, esc;
  {
    int r = ncell / Ww, c = ncell - r * Ww;
    float fc = (float)c, fr = (float)r;
    ex1 = rintf((2.0f * fc) / 0.6f);
    ex2 = rintf((2.0f * fc + 12.0f) / 0.6f);
    ey1 = rintf((2.0f * fr) / 0.6f);
    ey2 = rintf((2.0f * fr + 12.0f) / 0.6f);
    ebw = ex2 - ex1 + 1.0f; ebh = ey2 - ey1 + 1.0f;
    esc = sc[ncell];
  }
  lds_barrier();

  // ---- Rounds: bitboard Jacobi, QUAD-EVAL per barrier (lean body);
  //      LDS-only barrier/round; termination checked every 2 rounds. ----
  const int t = tid;
  unsigned long long regD[12];
  unsigned long long u_self = 0ull, k_self = 0ull;
  if (t < NW) {
    #pragma unroll
    for (int b = 0; b < 12; ++b) regD[b] = s_D[b][t];
    u_self = U[t];
    k_self = K[t];
  }

  // Register-lean sliding-window eval; write-through on change.
  auto eval = [&]() -> bool {
    unsigned long long anyU, anyK;
    {
      unsigned long long ua = U[t - 3], ka = K[t - 3];
      anyU = ua & regD[6];                 // -192
      anyK = ka & regD[6];
    }
    {
      unsigned long long ub = U[t - 2], kb = K[t - 2];
      unsigned long long uc = U[t - 1], kc = K[t - 1];
      anyU |= ((uc << 32) | (ub >> 32)) & regD[4];   // -96
      anyK |= ((kc << 32) | (kb >> 32)) & regD[4];
      anyU |= ((uc << 33) | (ub >> 31)) & regD[8];   // -97
      anyK |= ((kc << 33) | (kb >> 31)) & regD[8];
      anyU |= ((uc << 31) | (ub >> 33)) & regD[9];   // -95
      anyK |= ((kc << 31) | (kb >> 33)) & regD[9];
      anyU |= ((u_self << 1) | (uc >> 63)) & regD[0];  // -1
      anyK |= ((k_self << 1) | (kc >> 63)) & regD[0];
      anyU |= ((u_self << 2) | (uc >> 62)) & regD[2];  // -2
      anyK |= ((k_self << 2) | (kc >> 62)) & regD[2];
    }
    {
      unsigned long long ud = U[t + 1], kd = K[t + 1];
      unsigned long long ue = U[t + 2], ke = K[t + 2];
      anyU |= ((u_self >> 1) | (ud << 63)) & regD[1];  // +1
      anyK |= ((k_self >> 1) | (kd << 63)) & regD[1];
      anyU |= ((u_self >> 2) | (ud << 62)) & regD[3];  // +2
      anyK |= ((k_self >> 2) | (kd << 62)) & regD[3];
      anyU |= ((ud >> 32) | (ue << 32)) & regD[5];     // +96
      anyK |= ((kd >> 32) | (ke << 32)) & regD[5];
      anyU |= ((ud >> 31) | (ue << 33)) & regD[10];    // +95
      anyK |= ((kd >> 31) | (ke << 33)) & regD[10];
      anyU |= ((ud >> 33) | (ue << 31)) & regD[11];    // +97
      anyK |= ((kd >> 33) | (ke << 31)) & regD[11];
    }
    {
      unsigned long long uf = U[t + 3], kf = K[t + 3];
      anyU |= uf & regD[7];                // +192
      anyK |= kf & regD[7];
    }
    unsigned long long u2 = u_self & anyU & ~anyK;
    if (u2 != u_self) {
      k_self |= u_self & ~anyU & ~anyK;
      u_self = u2;
      U[t] = u_self; K[t] = k_self;        // write-through (sole writer)
      return true;
    }
    return false;
  };

  for (int it = 0; it < 3000; ++it) {
    const int pair = it >> 1;
    if ((it & 1) == 0 && tid == 0) s_ch[(pair + 1) % 3] = 0;  // reset NEXT pair's flag
    if (t < NW && u_self) {
      bool ch = eval();                    // up to 4 graph-steps per barrier;
      if (u_self) ch |= eval();            // each re-reads neighbors, picking
      if (u_self) ch |= eval();            // up same-interval updates
      if (u_self) ch |= eval();            // (monotone => any interleaving ok)
      if (ch) s_ch[pair % 3] = 1;          // benign race: all store 1
    }
    lds_barrier();
    if ((it & 1) && s_ch[pair % 3] == 0) break;   // uniform broadcast read
  }
  // K stable: last K writes precede the final (no-change) pair's barrier.

  // ---- Epilogue: this block's 1024-cell slice (prep hoisted) ----
  {
    const int n = ncell;
    float k = (float)((K[n >> 6] >> (n & 63)) & 1ull);
    v4a o;
    o.x = (ex1 + bb0.x * ebw) * k;
    o.y = (ey1 + bb0.y * ebh) * k;
    o.z = (ex2 + bb0.z * ebw) * k;
    o.w = (ey2 + bb0.w * ebh) * k;
    *reinterpret_cast<v4a*>(out + n * 5) = o;
    out[n * 5 + 4] = esc * k;
  }
}

} // namespace

extern "C" void kernel_launch(void* const* d_in, const int* in_sizes, int n_in,
                              void* d_out, int out_size, void* d_ws, size_t ws_size,
                              hipStream_t stream) {
  const float* cls  = (const float*)d_in[0];   // (96,96) f32
  const float* bbox = (const float*)d_in[1];   // (96,96,4) f32
  float* out = (float*)d_out;                  // (9216,5) f32
  hipLaunchKernelGGL(mtcnn_kernel, dim3(NBLK), dim3(NT), 0, stream,
                     cls, bbox, out);
}